// Round 1
// baseline (85.385 us; speedup 1.0000x reference)
//
#include <hip/hip_runtime.h>

#define DIVN 8
#define NB 32
#define NC 3
#define H 1024
#define W 1024
#define BH (H / DIVN)            // 128
#define BW (W / DIVN)            // 128
#define NBLK (NB * NC * DIVN * DIVN)  // 6144

// Stage 1: per (b,c,bi,bj) 128x128 block -> mean (f64 accum), min, max.
// One 256-thread workgroup per block; 16 float4 loads per thread.
__global__ __launch_bounds__(256) void block_stats_kernel(
    const float* __restrict__ x,
    float* __restrict__ mean_out,
    float* __restrict__ min_out,
    float* __restrict__ max_out) {
    const int gid = blockIdx.x;        // 0..6143  = ((b*3+c)*8 + bi)*8 + bj
    const int bj  = gid & 7;
    const int bi  = (gid >> 3) & 7;
    const int img = gid >> 6;          // b*3 + c
    const float* base = x + (size_t)img * (H * W) + (size_t)bi * BH * W + (size_t)bj * BW;

    const int tid = threadIdx.x;
    double s = 0.0;
    float mn = 3.402823466e38f;
    float mx = -3.402823466e38f;

    #pragma unroll
    for (int it = 0; it < 16; ++it) {
        const int idx = it * 256 + tid;     // 0..4095 (float4 units)
        const int row = idx >> 5;           // 32 float4 per 128-float row
        const int c4  = idx & 31;
        const float4 v = *reinterpret_cast<const float4*>(base + row * W + c4 * 4);
        s += (double)v.x + (double)v.y + (double)v.z + (double)v.w;
        mn = fminf(mn, fminf(fminf(v.x, v.y), fminf(v.z, v.w)));
        mx = fmaxf(mx, fmaxf(fmaxf(v.x, v.y), fmaxf(v.z, v.w)));
    }

    __shared__ double ssum[256];
    __shared__ float  smn[256];
    __shared__ float  smx[256];
    ssum[tid] = s; smn[tid] = mn; smx[tid] = mx;
    __syncthreads();
    for (int off = 128; off > 0; off >>= 1) {
        if (tid < off) {
            ssum[tid] += ssum[tid + off];
            smn[tid]   = fminf(smn[tid], smn[tid + off]);
            smx[tid]   = fmaxf(smx[tid], smx[tid + off]);
        }
        __syncthreads();
    }
    if (tid == 0) {
        mean_out[gid] = (float)(ssum[0] * (1.0 / 16384.0));
        min_out[gid]  = smn[0];
        max_out[gid]  = smx[0];
    }
}

// Stage 2: combine 6144 block stats -> scalar. 2048 (b, bi, bj) items,
// 3 channel pairs each. Single 256-thread workgroup.
__global__ __launch_bounds__(256) void pair_reduce_kernel(
    const float* __restrict__ mean_s,
    const float* __restrict__ min_s,
    const float* __restrict__ max_s,
    float* __restrict__ out) {
    const int tid = threadIdx.x;
    double acc = 0.0;

    for (int item = tid; item < NB * DIVN * DIVN; item += 256) {
        const int p = item & 63;        // bi*8 + bj
        const int b = item >> 6;
        const int i0 = (b * 3 + 0) * 64 + p;
        const int i1 = (b * 3 + 1) * 64 + p;
        const int i2 = (b * 3 + 2) * 64 + p;

        const float m0 = mean_s[i0], m1 = mean_s[i1], m2 = mean_s[i2];
        const float n0 = min_s[i0],  n1 = min_s[i1],  n2 = min_s[i2];
        const float x0 = max_s[i0],  x1 = max_s[i1],  x2 = max_s[i2];

        // pair (0,1)
        if (!((n0 > x1) || (x0 < n1))) { const float d = m0 - m1; acc += (double)(d * d); }
        // pair (1,2)
        if (!((n1 > x2) || (x1 < n2))) { const float d = m1 - m2; acc += (double)(d * d); }
        // pair (0,2)
        if (!((n0 > x2) || (x0 < n2))) { const float d = m0 - m2; acc += (double)(d * d); }
    }

    __shared__ double sacc[256];
    sacc[tid] = acc;
    __syncthreads();
    for (int off = 128; off > 0; off >>= 1) {
        if (tid < off) sacc[tid] += sacc[tid + off];
        __syncthreads();
    }
    if (tid == 0) out[0] = (float)(sacc[0] * (1.0 / (DIVN * DIVN)));
}

extern "C" void kernel_launch(void* const* d_in, const int* in_sizes, int n_in,
                              void* d_out, int out_size, void* d_ws, size_t ws_size,
                              hipStream_t stream) {
    const float* x = (const float*)d_in[0];
    float* out = (float*)d_out;

    float* ws   = (float*)d_ws;
    float* mean = ws;
    float* mn   = ws + NBLK;
    float* mx   = ws + 2 * NBLK;

    block_stats_kernel<<<NBLK, 256, 0, stream>>>(x, mean, mn, mx);
    pair_reduce_kernel<<<1, 256, 0, stream>>>(mean, mn, mx, out);
}

// Round 3
// 69.031 us; speedup vs baseline: 1.2369x; 1.2369x over previous
//
#include <hip/hip_runtime.h>

#define DIVN 8
#define NB 32
#define NC 3
#define NIMG (NB * NC)                 // 96
#define NBLK (NIMG * DIVN * DIVN)     // 6144
#define ROWS_PER_CHUNK 64
#define NCHUNK (NIMG * 16)            // 1536 : img*16 + bi*2 + half

typedef float floatx4 __attribute__((ext_vector_type(4)));

// Stage 1: each WG owns a contiguous 256 KB chunk (64 rows of one image).
// Thread tid always reads float4-column tid -> its bj = tid>>5 is FIXED,
// so stats accumulate in scalar registers; cross-lane reduce via shfl.
__global__ __launch_bounds__(256) void stats_kernel(
    const float* __restrict__ x,
    double* __restrict__ wsum,   // [2][NBLK]
    float* __restrict__ wmn,     // [2][NBLK]
    float* __restrict__ wmx) {   // [2][NBLK]
    const int ch  = blockIdx.x;           // 0..1535
    const int tid = threadIdx.x;          // 0..255
    const float* base = x + (size_t)ch * (ROWS_PER_CHUNK * 1024) + tid * 4;

    double s = 0.0;
    float mn = 3.402823466e38f;
    float mx = -3.402823466e38f;

    #pragma unroll 8
    for (int i = 0; i < ROWS_PER_CHUNK; ++i) {
        const floatx4 v = __builtin_nontemporal_load(
            reinterpret_cast<const floatx4*>(base + (size_t)i * 1024));
        const float ps = (v.x + v.y) + (v.z + v.w);
        s += (double)ps;
        mn = fminf(mn, fminf(fminf(v.x, v.y), fminf(v.z, v.w)));
        mx = fmaxf(mx, fmaxf(fmaxf(v.x, v.y), fmaxf(v.z, v.w)));
    }

    // Reduce within 32-lane groups (one group per bj); no LDS needed.
    for (int off = 16; off > 0; off >>= 1) {
        s  += __shfl_down(s, off, 32);
        mn  = fminf(mn, __shfl_down(mn, off, 32));
        mx  = fmaxf(mx, __shfl_down(mx, off, 32));
    }

    if ((tid & 31) == 0) {
        const int bj   = tid >> 5;
        const int half = ch & 1;
        const int bi   = (ch >> 1) & 7;
        const int img  = ch >> 4;
        const int g    = img * 64 + bi * 8 + bj;
        wsum[half * NBLK + g] = s;
        wmn [half * NBLK + g] = mn;
        wmx [half * NBLK + g] = mx;
    }
}

// Stage 2: combine halves, compute pair terms, reduce to scalar.
__global__ __launch_bounds__(256) void pair_reduce_kernel(
    const double* __restrict__ wsum,
    const float* __restrict__ wmn,
    const float* __restrict__ wmx,
    float* __restrict__ out) {
    const int tid = threadIdx.x;
    double acc = 0.0;

    for (int item = tid; item < NB * DIVN * DIVN; item += 256) {
        const int p = item & 63;        // bi*8 + bj
        const int b = item >> 6;
        float m[3], n[3], X[3];
        #pragma unroll
        for (int c = 0; c < 3; ++c) {
            const int i = (b * 3 + c) * 64 + p;
            m[c] = (float)((wsum[i] + wsum[NBLK + i]) * (1.0 / 16384.0));
            n[c] = fminf(wmn[i], wmn[NBLK + i]);
            X[c] = fmaxf(wmx[i], wmx[NBLK + i]);
        }
        if (!((n[0] > X[1]) || (X[0] < n[1]))) { const float d = m[0] - m[1]; acc += (double)(d * d); }
        if (!((n[1] > X[2]) || (X[1] < n[2]))) { const float d = m[1] - m[2]; acc += (double)(d * d); }
        if (!((n[0] > X[2]) || (X[0] < n[2]))) { const float d = m[0] - m[2]; acc += (double)(d * d); }
    }

    __shared__ double sacc[256];
    sacc[tid] = acc;
    __syncthreads();
    for (int off = 128; off > 0; off >>= 1) {
        if (tid < off) sacc[tid] += sacc[tid + off];
        __syncthreads();
    }
    if (tid == 0) out[0] = (float)(sacc[0] * (1.0 / (DIVN * DIVN)));
}

extern "C" void kernel_launch(void* const* d_in, const int* in_sizes, int n_in,
                              void* d_out, int out_size, void* d_ws, size_t ws_size,
                              hipStream_t stream) {
    const float* x = (const float*)d_in[0];
    float* out = (float*)d_out;

    // ws layout: doubles first (alignment), then floats.
    double* wsum = (double*)d_ws;                    // 2*NBLK doubles
    float*  wmn  = (float*)(wsum + 2 * NBLK);        // 2*NBLK floats
    float*  wmx  = wmn + 2 * NBLK;                   // 2*NBLK floats

    stats_kernel<<<NCHUNK, 256, 0, stream>>>(x, wsum, wmn, wmx);
    pair_reduce_kernel<<<1, 256, 0, stream>>>(wsum, wmn, wmx, out);
}